// Round 8
// baseline (63.655 us; speedup 1.0000x reference)
//
#include <hip/hip_runtime.h>
#include <hip/hip_bf16.h>

// KPConv fused kernel for MI355X (gfx950) — round 8.
// B=4, M=16384, K_NB=32, D_IN=64, D_OUT=64, K_PTS=15, SIGMA=1.
//
// R8 vs R7 (R7 = 53.9 us kernel, latency-bound at 4 blocks/CU):
//  * stg aliased INTO fk: stg[wv][j] (512 B, slot-swizzled float4[32]) lives in
//    the first 512 B of fk row wv*4+j. It is fully read in iteration j before
//    that row's fk write (same wave, in-order LDS) -> safe. LDS 40960 -> 32768 B
//    -> exactly 5 blocks/CU (was 4). __launch_bounds__(256,5).
//  * Bank pattern unchanged (row stride 2048 == old stride 512 mod 128).
//  * All other code identical to R7 (verified swizzles, kappa layout, pipeline).

#define BATCH 4
#define MPTS  16384
#define KNB   32
#define DIN   64
#define DOUT  64
#define KP    15
#define K2P   1024          // padded K: kappa = n*64 + (p>>2)*16 + t*4 + (p&3), d = 4n+t
#define KSTEPS (K2P/32)     // 32
#define ROWB  (K2P*2)       // 2048 bytes per fk row
#define PTS   (BATCH*MPTS)  // 65536
#define PPB   16            // points per block
#define NBLK  (PTS/PPB)     // 4096
#define WBELEMS (K2P*DOUT)  // 65536 ushorts = 131072 B

typedef __bf16 bf16x8 __attribute__((ext_vector_type(8)));
typedef float  f32x4  __attribute__((ext_vector_type(4)));
typedef unsigned short u16x8 __attribute__((ext_vector_type(8)));

static __device__ __forceinline__ unsigned short f2b(float x) {
    __bf16 h = (__bf16)x;              // RNE convert
    return __builtin_bit_cast(unsigned short, h);
}

// ---- prep: W [15][64][64] f32 -> padded bf16 B-fragments ----
// wb[((et*KSTEPS+ks)*64+lane)*8+i] = B[kappa][e]; kappa=ks*32+(lane>>4)*8+i;
// n=kap>>6, g=(kap>>4)&3, t=(kap>>2)&3, r=kap&3; p=4g+r, d=4n+t; p==15 -> 0.
__global__ void prep_wb(const float* __restrict__ W, unsigned short* __restrict__ wb) {
    int idx = blockIdx.x * 256 + threadIdx.x;
    if (idx >= WBELEMS) return;
    int i    = idx & 7;
    int lane = (idx >> 3) & 63;
    int ks   = (idx >> 9) & 31;
    int et   = idx >> 14;
    int kap  = ks * 32 + ((lane >> 4) << 3) + i;
    int n = kap >> 6;
    int g = (kap >> 4) & 3;
    int t = (kap >> 2) & 3;
    int r = kap & 3;
    int p = g * 4 + r;
    int d = n * 4 + t;
    int e = et * 16 + (lane & 15);
    float v = (p < KP) ? W[(p * DIN + d) * DOUT + e] : 0.f;
    wb[idx] = f2b(v);
}

// ---- prep: F f32 -> bf16 (8 elems / thread) ----
__global__ void f2bf_kernel(const float* __restrict__ src, unsigned short* __restrict__ dst, int n8) {
    int i = blockIdx.x * 256 + threadIdx.x;
    if (i >= n8) return;
    const float4* s = reinterpret_cast<const float4*>(src) + (size_t)i * 2;
    float4 a = s[0], b = s[1];
    u16x8 o;
    o[0] = f2b(a.x); o[1] = f2b(a.y); o[2] = f2b(a.z); o[3] = f2b(a.w);
    o[4] = f2b(b.x); o[5] = f2b(b.y); o[6] = f2b(b.z); o[7] = f2b(b.w);
    *(reinterpret_cast<u16x8*>(dst) + i) = o;
}

__global__ __launch_bounds__(256, 5)
void kpconv_main(const float* __restrict__ X, const unsigned short* __restrict__ FB,
                 const int* __restrict__ NB, const float* __restrict__ Q,
                 const unsigned short* __restrict__ WB, float* __restrict__ OUT) {
    // 32768 B total. stg[wv][j] (float4[32], slot-swizzled) aliases the first
    // 512 B of fk row wv*4+j; consumed before that row's fk write (same wave).
    __shared__ unsigned short fk[16 * K2P];

    char* const fkb = reinterpret_cast<char*>(fk);

    const int tid  = threadIdx.x;
    const int wv   = tid >> 6;    // wave 0..3 = e-tile
    const int lane = tid & 63;
    const int g16  = lane >> 4;   // 0..3
    const int r16  = lane & 15;   // 0..15

    // per-lane kernel-point constants; p=15 pad row gets far-away virtual point -> h=0
    float qx = 1.0e3f, qy = 0.f, qz = 0.f;
    if (r16 < KP) { qx = Q[r16 * 3 + 0]; qy = Q[r16 * 3 + 1]; qz = Q[r16 * 3 + 2]; }
    const float qq   = qx * qx + qy * qy + qz * qz;
    const float nq2x = -2.f * qx, nq2y = -2.f * qy, nq2z = -2.f * qz;

    // XCD-aware mapping: XCD (bid&7) owns one batch's 8192-point span
    const int bid     = blockIdx.x;
    const int base_pt = (bid & 7) * (PTS / 8) + (bid >> 3) * PPB;
    const int boff    = (base_pt >> 14) * MPTS;   // uniform per block
    const int pid0    = base_pt + wv * 4;

    // ---- stage r-vectors (rx,ry,rz,|r|^2) into fk-row heads; slot-swizzled ----
    #pragma unroll
    for (int e = 0; e < 2; ++e) {
        int ent = lane + e * 64;
        int j = ent >> 5, k = ent & 31;
        int pid = pid0 + j;
        int nb  = NB[(size_t)pid * KNB + k];
        int gidx = boff + nb;
        const float* xn = X + (size_t)gidx * 3;
        const float* xc = X + (size_t)pid * 3;
        float rx = xn[0] - xc[0];
        float ry = xn[1] - xc[1];
        float rz = xn[2] - xc[2];
        float rr = fmaf(rx, rx, fmaf(ry, ry, rz * rz));
        int slot = (k & 24) | ((k ^ (k >> 3)) & 7);
        *reinterpret_cast<float4*>(fkb + (wv * 4 + j) * ROWB + slot * 16) =
            make_float4(rx, ry, rz, rr);   // same-wave produce/consume
    }

    // ---- 2-deep pipelined F gathers: lane owns neighbors g16*8..+7, channels 4*r16..+3 ----
    union U { uint2 d; unsigned short s[4]; };
    U L[2][8];

    auto issue_gather = [&](int j, U* Lj) {
        const int* nbp = NB + (size_t)(pid0 + j) * KNB + g16 * 8;
        int4 a = *reinterpret_cast<const int4*>(nbp);
        int4 b = *reinterpret_cast<const int4*>(nbp + 4);
        int g[8] = {a.x, a.y, a.z, a.w, b.x, b.y, b.z, b.w};
        #pragma unroll
        for (int i = 0; i < 8; ++i)
            Lj[i].d = *reinterpret_cast<const uint2*>(
                FB + ((size_t)(boff + g[i]) << 6) + (r16 << 2));
    };

    issue_gather(0, L[0]);
    issue_gather(1, L[1]);

    // ---------------- stage 1: 4 points per wave, pipelined ----------------
    #pragma unroll
    for (int j = 0; j < 4; ++j) {
        const int row = wv * 4 + j;                // fk row (0..15)

        // A fragment: h(p=r16, k=g16*8+i), dot-form d^2 clamped to 0
        bf16x8 ah;
        #pragma unroll
        for (int i = 0; i < 8; ++i) {
            float4 rv = *reinterpret_cast<const float4*>(
                fkb + row * ROWB + (g16 * 8 + (i ^ g16)) * 16);
            float d2 = fmaf(rv.x, nq2x, fmaf(rv.y, nq2y, fmaf(rv.z, nq2z, rv.w + qq)));
            d2 = fmaxf(d2, 0.f);
            ah[i] = (__bf16)fmaxf(1.f - __builtin_amdgcn_sqrtf(d2), 0.f);
        }

        // extract B fragments from this j's gather buffer, then reuse it for j+2
        bf16x8 bfr[4];
        #pragma unroll
        for (int t = 0; t < 4; ++t)
            #pragma unroll
            for (int i = 0; i < 8; ++i)
                bfr[t][i] = __builtin_bit_cast(__bf16, L[j & 1][i].s[t]);

        if (j < 2) issue_gather(j + 2, L[j & 1]);

        const f32x4 z = {0.f, 0.f, 0.f, 0.f};
        f32x4 accs[4];
        #pragma unroll
        for (int t = 0; t < 4; ++t)
            accs[t] = __builtin_amdgcn_mfma_f32_16x16x32_bf16(ah, bfr[t], z, 0, 0, 0);

        // fk write: lane holds kappa r16*64+g16*16 .. +15 (32 B) -> 2x ds_write_b128
        // (overwrites this row's stg head only AFTER all its reads above)
        bf16x8 w0, w1;
        #pragma unroll
        for (int r = 0; r < 4; ++r) {
            w0[r]     = (__bf16)accs[0][r];
            w0[4 + r] = (__bf16)accs[1][r];
            w1[r]     = (__bf16)accs[2][r];
            w1[4 + r] = (__bf16)accs[3][r];
        }
        int swz  = (row & 7) ^ (r16 & 7);
        int off0 = row * ROWB + (r16 * 8 + ((g16 * 2 + 0) ^ swz)) * 16;
        int off1 = row * ROWB + (r16 * 8 + ((g16 * 2 + 1) ^ swz)) * 16;
        *reinterpret_cast<bf16x8*>(fkb + off0) = w0;
        *reinterpret_cast<bf16x8*>(fkb + off1) = w1;
    }

    __syncthreads();   // all 16 fk rows visible to all waves

    // ---------------- stage 2: [16 x 1024] x [1024 x 16] per wave ----------------
    const unsigned short* wbp = WB + ((size_t)(wv * KSTEPS) * 64 + lane) * 8;
    asm volatile("" : "+v"(wbp));   // defeat LICM: stream W from L1/L2, not 128 regs

    f32x4 o = {0.f, 0.f, 0.f, 0.f};
    #pragma unroll
    for (int ks = 0; ks < KSTEPS; ++ks) {
        bf16x8 b = *reinterpret_cast<const bf16x8*>(wbp + ks * 512);
        int stored = (ks * 4 + g16) ^ (r16 & 7) ^ ((ks >> 1) & 7);
        bf16x8 a = *reinterpret_cast<const bf16x8*>(fkb + r16 * ROWB + stored * 16);
        o = __builtin_amdgcn_mfma_f32_16x16x32_bf16(a, b, o, 0, 0, 0);
    }

    #pragma unroll
    for (int r = 0; r < 4; ++r) {
        int pid = base_pt + g16 * 4 + r;
        OUT[(size_t)pid * DOUT + wv * 16 + r16] = o[r];
    }
}

extern "C" void kernel_launch(void* const* d_in, const int* in_sizes, int n_in,
                              void* d_out, int out_size, void* d_ws, size_t ws_size,
                              hipStream_t stream) {
    const float* X = (const float*)d_in[0];
    const float* F = (const float*)d_in[1];
    const int*   N = (const int*)d_in[2];
    const float* Q = (const float*)d_in[3];
    const float* W = (const float*)d_in[4];
    float* OUT = (float*)d_out;
    unsigned short* WB = (unsigned short*)d_ws;          // 131072 B
    unsigned short* FB = WB + WBELEMS;                   // 8388608 B

    prep_wb<<<(WBELEMS + 255) / 256, 256, 0, stream>>>(W, WB);

    const int n8 = PTS * DIN / 8;                        // 524288
    f2bf_kernel<<<(n8 + 255) / 256, 256, 0, stream>>>(F, FB, n8);

    kpconv_main<<<NBLK, 256, 0, stream>>>(X, FB, N, Q, WB, OUT);
}

// Round 9
// 61.274 us; speedup vs baseline: 1.0389x; 1.0389x over previous
//
#include <hip/hip_runtime.h>
#include <hip/hip_bf16.h>

// KPConv fused kernel for MI355X (gfx950) — round 9.
// B=4, M=16384, K_NB=32, D_IN=64, D_OUT=64, K_PTS=15, SIGMA=1.
//
// R9 vs R8 (R8 = 53.9 us kernel, latency-bound, occupancy NOT LDS-limited):
//  * 2 tiles per block (PPB=32, 2048 blocks), cross-tile software pipeline:
//    during tile0's stage-2 MFMA loop, tile1's NB/X loads are issued into
//    registers (phase A, sched_barrier-fenced), stg ds_writes + first F-gathers
//    complete after the loop (phase C). Tile1 starts with staging resident.
//  * stg back in its own 8 KB (wave-private, no barrier coupling). LDS 40960.
//  * prep_wb + f2bf merged into one kernel (one less launch).
//  * All verified layouts/swizzles unchanged from R6/R7/R8.

#define BATCH 4
#define MPTS  16384
#define KNB   32
#define DIN   64
#define DOUT  64
#define KP    15
#define K2P   1024          // padded K: kappa = n*64 + (p>>2)*16 + t*4 + (p&3), d = 4n+t
#define KSTEPS (K2P/32)     // 32
#define ROWB  (K2P*2)       // 2048 bytes per fk row
#define PTS   (BATCH*MPTS)  // 65536
#define PPB   32            // points per block (2 tiles of 16)
#define NBLK  (PTS/PPB)     // 2048
#define WBELEMS (K2P*DOUT)  // 65536 ushorts = 131072 B
#define WBBLK (WBELEMS/256) // 256 prep blocks
#define FBBLK (PTS*DIN/8/256) // 2048 prep blocks

typedef __bf16 bf16x8 __attribute__((ext_vector_type(8)));
typedef float  f32x4  __attribute__((ext_vector_type(4)));
typedef unsigned short u16x8 __attribute__((ext_vector_type(8)));

static __device__ __forceinline__ unsigned short f2b(float x) {
    __bf16 h = (__bf16)x;              // RNE convert
    return __builtin_bit_cast(unsigned short, h);
}

// ---- merged prep: blocks [0,256) build WB fragments; [256,2304) convert F ----
__global__ void prep_all(const float* __restrict__ W, const float* __restrict__ F,
                         unsigned short* __restrict__ wb, unsigned short* __restrict__ fb) {
    int bid = blockIdx.x;
    if (bid < WBBLK) {
        int idx = bid * 256 + threadIdx.x;
        int i    = idx & 7;
        int lane = (idx >> 3) & 63;
        int ks   = (idx >> 9) & 31;
        int et   = idx >> 14;
        int kap  = ks * 32 + ((lane >> 4) << 3) + i;
        int n = kap >> 6;
        int g = (kap >> 4) & 3;
        int t = (kap >> 2) & 3;
        int r = kap & 3;
        int p = g * 4 + r;
        int d = n * 4 + t;
        int e = et * 16 + (lane & 15);
        float v = (p < KP) ? W[(p * DIN + d) * DOUT + e] : 0.f;
        wb[idx] = f2b(v);
    } else {
        int i = (bid - WBBLK) * 256 + threadIdx.x;    // exactly PTS*DIN/8 threads
        const float4* s = reinterpret_cast<const float4*>(F) + (size_t)i * 2;
        float4 a = s[0], b = s[1];
        u16x8 o;
        o[0] = f2b(a.x); o[1] = f2b(a.y); o[2] = f2b(a.z); o[3] = f2b(a.w);
        o[4] = f2b(b.x); o[5] = f2b(b.y); o[6] = f2b(b.z); o[7] = f2b(b.w);
        *(reinterpret_cast<u16x8*>(fb) + i) = o;
    }
}

__global__ __launch_bounds__(256, 4)
void kpconv_main(const float* __restrict__ X, const unsigned short* __restrict__ FB,
                 const int* __restrict__ NB, const float* __restrict__ Q,
                 const unsigned short* __restrict__ WB, float* __restrict__ OUT) {
    __shared__ unsigned short fk[16 * K2P];   // 32768 B, swizzled 16B chunks
    __shared__ float4 stg[4][4][KNB];         //  8192 B, wave-private, slot-swizzled

    char* const fkb = reinterpret_cast<char*>(fk);

    const int tid  = threadIdx.x;
    const int wv   = tid >> 6;    // wave 0..3 = e-tile
    const int lane = tid & 63;
    const int g16  = lane >> 4;   // 0..3
    const int r16  = lane & 15;   // 0..15

    // per-lane kernel-point constants; p=15 pad row gets far-away virtual point -> h=0
    float qx = 1.0e3f, qy = 0.f, qz = 0.f;
    if (r16 < KP) { qx = Q[r16 * 3 + 0]; qy = Q[r16 * 3 + 1]; qz = Q[r16 * 3 + 2]; }
    const float qq   = qx * qx + qy * qy + qz * qz;
    const float nq2x = -2.f * qx, nq2y = -2.f * qy, nq2z = -2.f * qz;

    // XCD-aware mapping: XCD (bid&7) owns one batch's 8192-point span
    const int bid     = blockIdx.x;
    const int base_pt = (bid & 7) * (PTS / 8) + (bid >> 3) * PPB;
    const int boff    = (base_pt >> 14) * MPTS;   // uniform per block

    union U { uint2 d; unsigned short s[4]; };
    U L[2][8];

    // F gathers for point pid_j: lane owns neighbors g16*8..+7, channels 4*r16..+3
    auto issue_gather = [&](int pid_j, U* Lj) {
        const int* nbp = NB + (size_t)pid_j * KNB + g16 * 8;
        int4 a = *reinterpret_cast<const int4*>(nbp);
        int4 b = *reinterpret_cast<const int4*>(nbp + 4);
        int g[8] = {a.x, a.y, a.z, a.w, b.x, b.y, b.z, b.w};
        #pragma unroll
        for (int i = 0; i < 8; ++i)
            Lj[i].d = *reinterpret_cast<const uint2*>(
                FB + ((size_t)(boff + g[i]) << 6) + (r16 << 2));
    };

    // full staging for this wave's 4 points of tile starting at tp (loads+writes)
    auto stage_stg = [&](int tp) {
        #pragma unroll
        for (int e = 0; e < 2; ++e) {
            int ent = lane + e * 64;
            int j = ent >> 5, k = ent & 31;
            int pid = tp + wv * 4 + j;
            int nb  = NB[(size_t)pid * KNB + k];
            int gidx = boff + nb;
            const float* xn = X + (size_t)gidx * 3;
            const float* xc = X + (size_t)pid * 3;
            float rx = xn[0] - xc[0];
            float ry = xn[1] - xc[1];
            float rz = xn[2] - xc[2];
            float rr = fmaf(rx, rx, fmaf(ry, ry, rz * rz));
            int slot = (k & 24) | ((k ^ (k >> 3)) & 7);
            stg[wv][j][slot] = make_float4(rx, ry, rz, rr);
        }
    };

    // ---- prologue: tile 0 staging + first two gathers ----
    stage_stg(base_pt);
    issue_gather(base_pt + wv * 4 + 0, L[0]);
    issue_gather(base_pt + wv * 4 + 1, L[1]);

    #pragma unroll
    for (int tile = 0; tile < 2; ++tile) {
        const int tp   = base_pt + tile * 16;
        const int pid0 = tp + wv * 4;

        // ---------------- stage 1: 4 points per wave, pipelined ----------------
        #pragma unroll
        for (int j = 0; j < 4; ++j) {
            const int row = wv * 4 + j;

            bf16x8 ah;
            #pragma unroll
            for (int i = 0; i < 8; ++i) {
                float4 rv = stg[wv][j][g16 * 8 + (i ^ g16)];
                float d2 = fmaf(rv.x, nq2x, fmaf(rv.y, nq2y, fmaf(rv.z, nq2z, rv.w + qq)));
                d2 = fmaxf(d2, 0.f);
                ah[i] = (__bf16)fmaxf(1.f - __builtin_amdgcn_sqrtf(d2), 0.f);
            }

            bf16x8 bfr[4];
            #pragma unroll
            for (int t = 0; t < 4; ++t)
                #pragma unroll
                for (int i = 0; i < 8; ++i)
                    bfr[t][i] = __builtin_bit_cast(__bf16, L[j & 1][i].s[t]);

            if (j < 2) issue_gather(pid0 + j + 2, L[j & 1]);

            const f32x4 z = {0.f, 0.f, 0.f, 0.f};
            f32x4 accs[4];
            #pragma unroll
            for (int t = 0; t < 4; ++t)
                accs[t] = __builtin_amdgcn_mfma_f32_16x16x32_bf16(ah, bfr[t], z, 0, 0, 0);

            bf16x8 w0, w1;
            #pragma unroll
            for (int r = 0; r < 4; ++r) {
                w0[r]     = (__bf16)accs[0][r];
                w0[4 + r] = (__bf16)accs[1][r];
                w1[r]     = (__bf16)accs[2][r];
                w1[4 + r] = (__bf16)accs[3][r];
            }
            int swz  = (row & 7) ^ (r16 & 7);
            int off0 = row * ROWB + (r16 * 8 + ((g16 * 2 + 0) ^ swz)) * 16;
            int off1 = row * ROWB + (r16 * 8 + ((g16 * 2 + 1) ^ swz)) * 16;
            *reinterpret_cast<bf16x8*>(fkb + off0) = w0;
            *reinterpret_cast<bf16x8*>(fkb + off1) = w1;
        }

        __syncthreads();   // all 16 fk rows visible to all waves

        // ---- phase A (tile 0 only): issue next tile's staging loads into regs ----
        int   A_nb[2];
        float A_xn[2][3], A_xc[2][3];
        int4  A_ga[2][2];
        if (tile == 0) {
            const int tp1 = base_pt + 16;
            #pragma unroll
            for (int e = 0; e < 2; ++e) {
                int ent = lane + e * 64;
                int j = ent >> 5, k = ent & 31;
                int pid = tp1 + wv * 4 + j;
                int nb  = NB[(size_t)pid * KNB + k];
                A_nb[e] = nb;
                const float* xn = X + (size_t)(boff + nb) * 3;
                const float* xc = X + (size_t)pid * 3;
                #pragma unroll
                for (int c = 0; c < 3; ++c) { A_xn[e][c] = xn[c]; A_xc[e][c] = xc[c]; }
            }
            #pragma unroll
            for (int j2 = 0; j2 < 2; ++j2) {
                const int* nbp = NB + (size_t)(tp1 + wv * 4 + j2) * KNB + g16 * 8;
                A_ga[j2][0] = *reinterpret_cast<const int4*>(nbp);
                A_ga[j2][1] = *reinterpret_cast<const int4*>(nbp + 4);
            }
            __builtin_amdgcn_sched_barrier(0);   // keep phase-A issues above the MFMA loop
        }

        // ---------------- stage 2: [16 x 1024] x [1024 x 16] per wave ----------------
        const unsigned short* wbp = WB + ((size_t)(wv * KSTEPS) * 64 + lane) * 8;
        asm volatile("" : "+v"(wbp));   // defeat LICM: stream W from L1/L2, not 128 regs

        f32x4 o = {0.f, 0.f, 0.f, 0.f};
        #pragma unroll
        for (int ks = 0; ks < KSTEPS; ++ks) {
            bf16x8 b = *reinterpret_cast<const bf16x8*>(wbp + ks * 512);
            int stored = (ks * 4 + g16) ^ (r16 & 7) ^ ((ks >> 1) & 7);
            bf16x8 a = *reinterpret_cast<const bf16x8*>(fkb + r16 * ROWB + stored * 16);
            o = __builtin_amdgcn_mfma_f32_16x16x32_bf16(a, b, o, 0, 0, 0);
        }

        // ---- phase C (tile 0 only): finish next tile staging + first gathers ----
        if (tile == 0) {
            #pragma unroll
            for (int e = 0; e < 2; ++e) {
                int ent = lane + e * 64;
                int j = ent >> 5, k = ent & 31;
                float rx = A_xn[e][0] - A_xc[e][0];
                float ry = A_xn[e][1] - A_xc[e][1];
                float rz = A_xn[e][2] - A_xc[e][2];
                float rr = fmaf(rx, rx, fmaf(ry, ry, rz * rz));
                int slot = (k & 24) | ((k ^ (k >> 3)) & 7);
                stg[wv][j][slot] = make_float4(rx, ry, rz, rr);
            }
            #pragma unroll
            for (int j2 = 0; j2 < 2; ++j2) {
                int g[8] = {A_ga[j2][0].x, A_ga[j2][0].y, A_ga[j2][0].z, A_ga[j2][0].w,
                            A_ga[j2][1].x, A_ga[j2][1].y, A_ga[j2][1].z, A_ga[j2][1].w};
                #pragma unroll
                for (int i = 0; i < 8; ++i)
                    L[j2][i].d = *reinterpret_cast<const uint2*>(
                        FB + ((size_t)(boff + g[i]) << 6) + (r16 << 2));
            }
        }

        #pragma unroll
        for (int r = 0; r < 4; ++r) {
            int pid = tp + g16 * 4 + r;
            OUT[(size_t)pid * DOUT + wv * 16 + r16] = o[r];
        }

        if (tile == 0) __syncthreads();   // protect fk before tile1 overwrites
    }
}

extern "C" void kernel_launch(void* const* d_in, const int* in_sizes, int n_in,
                              void* d_out, int out_size, void* d_ws, size_t ws_size,
                              hipStream_t stream) {
    const float* X = (const float*)d_in[0];
    const float* F = (const float*)d_in[1];
    const int*   N = (const int*)d_in[2];
    const float* Q = (const float*)d_in[3];
    const float* W = (const float*)d_in[4];
    float* OUT = (float*)d_out;
    unsigned short* WB = (unsigned short*)d_ws;          // 131072 B
    unsigned short* FB = WB + WBELEMS;                   // 8388608 B

    prep_all<<<WBBLK + FBBLK, 256, 0, stream>>>(W, F, WB, FB);
    kpconv_main<<<NBLK, 256, 0, stream>>>(X, FB, N, Q, WB, OUT);
}